// Round 3
// baseline (1886.415 us; speedup 1.0000x reference)
//
#include <hip/hip_runtime.h>
#include <stdint.h>

typedef unsigned short ushort_t;
typedef __attribute__((ext_vector_type(8))) __bf16 bf16x8;
typedef __attribute__((ext_vector_type(4))) float f32x4;

#define BM 128
#define BN 128
#define BK 32

#define M_TOTAL   51200
#define MTILES    400      // 51200 / 128
#define K1        2104
#define K1P       2112     // K padded to mult of 32
#define N1P       2176     // N1 padded to 17*128
#define N2        1024
#define SHIST     50
#define NGRP      1024     // 51200 / 50

__device__ __forceinline__ ushort_t f2bf(float f) {
  union { float f; unsigned u; } v; v.f = f;
  unsigned r = v.u + 0x7FFF + ((v.u >> 16) & 1);
  return (ushort_t)(r >> 16);
}

__device__ __forceinline__ void async_cp16(const void* g, void* l) {
  __builtin_amdgcn_global_load_lds(
      (const __attribute__((address_space(1))) void*)g,
      (__attribute__((address_space(3))) void*)l,
      16, 0, 0);
}

// ---------------- pack kernels ----------------
// W1 f32 [2104][2104] (k,n) -> W1T bf16 [2176][2112] (n,k), zero padded
__global__ void pack_w1t(const float* __restrict__ w1, ushort_t* __restrict__ w1t) {
  int k = blockIdx.x * 256 + threadIdx.x;
  int n = blockIdx.y;
  if (k >= K1P) return;
  ushort_t v = 0;
  if (k < K1 && n < K1) v = f2bf(w1[(long)k * K1 + n]);
  w1t[(long)n * K1P + k] = v;
}

// W2 f32 [2104][1024] -> W2T bf16 [1024][2112]
__global__ void pack_w2t(const float* __restrict__ w2, ushort_t* __restrict__ w2t) {
  int k = blockIdx.x * 256 + threadIdx.x;
  int n = blockIdx.y;
  if (k >= K1P) return;
  ushort_t v = 0;
  if (k < K1) v = f2bf(w2[(long)k * N2 + n]);
  w2t[(long)n * K1P + k] = v;
}

// xtail f32 [51200][64]: cols 0=vis, 1..4=bbox, 5..55=kp(51), 56..63=0
__global__ void pack_xtail(const float* __restrict__ vis,
                           const float* __restrict__ bbox,
                           const float* __restrict__ kp,
                           float* __restrict__ xtail) {
  int idx = blockIdx.x * 256 + threadIdx.x;   // 51200*64 total
  int r = idx >> 6, c = idx & 63;
  float v = 0.f;
  if (c == 0)       v = vis[r];
  else if (c < 5)   v = bbox[(long)r * 4 + (c - 1)];
  else if (c < 56)  v = kp[(long)r * 51 + (c - 5)];
  xtail[idx] = v;
}

__global__ void zero_accum(float* __restrict__ accum) {
  accum[blockIdx.x * 256 + threadIdx.x] = 0.f;
}

// ---------------- GEMM1: H = relu(X @ W1 + b1), X from emb(f32) + xtail(f32) ----------------
__global__ __launch_bounds__(256)
void gemm1(const float* __restrict__ emb, const float* __restrict__ xtail,
           const ushort_t* __restrict__ w1t, const float* __restrict__ b1,
           ushort_t* __restrict__ H, int mbase) {
  __shared__ __align__(16) ushort_t la[BM * BK];
  __shared__ __align__(16) ushort_t lb[BN * BK];
  const int tid  = threadIdx.x;
  const int lane = tid & 63;
  const int l15  = lane & 15;
  const int quad = lane >> 4;
  const int wave = tid >> 6;
  const int wm   = (wave & 1) * 64;
  const int wn   = (wave >> 1) * 64;
  const int m0   = blockIdx.y * BM;           // chunk-local
  const int n0   = blockIdx.x * BN;           // [0,2176)
  const long rowbase = (long)mbase + m0;      // global row

  f32x4 acc[4][4];
#pragma unroll
  for (int i = 0; i < 4; ++i)
#pragma unroll
    for (int j = 0; j < 4; ++j) {
      f32x4 z = {0.f, 0.f, 0.f, 0.f};
      acc[i][j] = z;
    }

  for (int ks = 0; ks < K1P / BK; ++ks) {
    const int k0 = ks * BK;
    // stage B (weights, bf16) via async copy
#pragma unroll
    for (int p = 0; p < 2; ++p) {
      int ci  = p * 256 + tid;
      int row = ci >> 2;
      int kc  = (ci & 3) * 8;
      async_cp16(&w1t[(long)(n0 + row) * K1P + k0 + kc], &lb[ci * 8]);
    }
    // stage A: 128x32, load f32, cvt->bf16, ds_write_b128. 2 chunks of 8/thread.
#pragma unroll
    for (int p = 0; p < 2; ++p) {
      int ci  = p * 256 + tid;
      int row = ci >> 2;
      int kc  = (ci & 3) * 8;
      long grow = rowbase + row;
      const float* src = (k0 < 2048)
          ? emb   + grow * 2048 + (k0 + kc)
          : xtail + grow * 64   + (k0 - 2048 + kc);
      f32x4 a0 = *(const f32x4*)src;
      f32x4 a1 = *(const f32x4*)(src + 4);
      bf16x8 v;
      v[0] = (__bf16)a0[0]; v[1] = (__bf16)a0[1];
      v[2] = (__bf16)a0[2]; v[3] = (__bf16)a0[3];
      v[4] = (__bf16)a1[0]; v[5] = (__bf16)a1[1];
      v[6] = (__bf16)a1[2]; v[7] = (__bf16)a1[3];
      *(bf16x8*)&la[ci * 8] = v;
    }
    __syncthreads();
    bf16x8 af[4], bfr[4];
#pragma unroll
    for (int i = 0; i < 4; ++i)
      af[i] = *(const bf16x8*)&la[(wm + i * 16 + l15) * BK + quad * 8];
#pragma unroll
    for (int j = 0; j < 4; ++j)
      bfr[j] = *(const bf16x8*)&lb[(wn + j * 16 + l15) * BK + quad * 8];
#pragma unroll
    for (int i = 0; i < 4; ++i)
#pragma unroll
      for (int j = 0; j < 4; ++j)
        acc[i][j] = __builtin_amdgcn_mfma_f32_16x16x32_bf16(af[i], bfr[j], acc[i][j], 0, 0, 0);
    __syncthreads();
  }

  // epilogue: bias + relu -> bf16 H (store only n < 2112)
#pragma unroll
  for (int i = 0; i < 4; ++i) {
    int mb = m0 + wm + i * 16 + quad * 4;     // chunk-local H row
#pragma unroll
    for (int j = 0; j < 4; ++j) {
      int n = n0 + wn + j * 16 + l15;
      if (n < K1P) {
        float bv = (n < K1) ? b1[n] : 0.f;
#pragma unroll
        for (int r = 0; r < 4; ++r) {
          float v = acc[i][j][r] + bv;
          v = fmaxf(v, 0.f);
          H[(long)(mb + r) * K1P + n] = f2bf(v);
        }
      }
    }
  }
}

// ---------------- GEMM2: accum[g][n] += sum_rows (H @ W2 + b2) * mask ----------------
__global__ __launch_bounds__(256)
void gemm2(const ushort_t* __restrict__ H, const ushort_t* __restrict__ w2t,
           const float* __restrict__ b2, const int* __restrict__ mask,
           float* __restrict__ accum, int mbase) {
  __shared__ __align__(16) ushort_t la[BM * BK];
  __shared__ __align__(16) ushort_t lb[BN * BK];
  __shared__ float sgrp[4 * BN];              // up to 4 history-groups per 128 rows
  const int tid  = threadIdx.x;
  const int lane = tid & 63;
  const int l15  = lane & 15;
  const int quad = lane >> 4;
  const int wave = tid >> 6;
  const int wm   = (wave & 1) * 64;
  const int wn   = (wave >> 1) * 64;
  const int m0   = blockIdx.y * BM;           // chunk-local
  const int n0   = blockIdx.x * BN;           // [0,1024)
  const int mg0  = mbase + m0;                // global row base
  const int g0   = mg0 / SHIST;

  f32x4 acc[4][4];
#pragma unroll
  for (int i = 0; i < 4; ++i)
#pragma unroll
    for (int j = 0; j < 4; ++j) {
      f32x4 z = {0.f, 0.f, 0.f, 0.f};
      acc[i][j] = z;
    }

  for (int ks = 0; ks < K1P / BK; ++ks) {
    const int k0 = ks * BK;
#pragma unroll
    for (int p = 0; p < 2; ++p) {
      int ci  = p * 256 + tid;
      int row = ci >> 2;
      int kc  = (ci & 3) * 8;
      async_cp16(&H[(long)(m0 + row) * K1P + k0 + kc], &la[ci * 8]);
    }
#pragma unroll
    for (int p = 0; p < 2; ++p) {
      int ci  = p * 256 + tid;
      int row = ci >> 2;
      int kc  = (ci & 3) * 8;
      async_cp16(&w2t[(long)(n0 + row) * K1P + k0 + kc], &lb[ci * 8]);
    }
    __syncthreads();
    bf16x8 af[4], bfr[4];
#pragma unroll
    for (int i = 0; i < 4; ++i)
      af[i] = *(const bf16x8*)&la[(wm + i * 16 + l15) * BK + quad * 8];
#pragma unroll
    for (int j = 0; j < 4; ++j)
      bfr[j] = *(const bf16x8*)&lb[(wn + j * 16 + l15) * BK + quad * 8];
#pragma unroll
    for (int i = 0; i < 4; ++i)
#pragma unroll
      for (int j = 0; j < 4; ++j)
        acc[i][j] = __builtin_amdgcn_mfma_f32_16x16x32_bf16(af[i], bfr[j], acc[i][j], 0, 0, 0);
    __syncthreads();
  }

  // epilogue: +b2, mask rows, partial group sums in LDS, then global atomics
  for (int z = tid; z < 4 * BN; z += 256) sgrp[z] = 0.f;
  __syncthreads();

#pragma unroll
  for (int i = 0; i < 4; ++i) {
    int mb = mg0 + wm + i * 16 + quad * 4;    // global row of reg r=0
#pragma unroll
    for (int j = 0; j < 4; ++j) {
      int cl = wn + j * 16 + l15;             // block-local col
      float bv = b2[n0 + cl];
      float s = 0.f;
      int gi_prev = mb / SHIST - g0;
#pragma unroll
      for (int r = 0; r < 4; ++r) {
        int m = mb + r;
        int gi = m / SHIST - g0;
        float mv = mask[m] ? 1.f : 0.f;
        float v = (acc[i][j][r] + bv) * mv;
        if (gi != gi_prev) {
          atomicAdd(&sgrp[gi_prev * BN + cl], s);
          s = 0.f; gi_prev = gi;
        }
        s += v;
      }
      atomicAdd(&sgrp[gi_prev * BN + cl], s);
    }
  }
  __syncthreads();

  for (int z = tid; z < 4 * BN; z += 256) {
    int gi = z >> 7, cl = z & 127;
    int g = g0 + gi;
    float v = sgrp[z];
    if (g < NGRP && v != 0.f)
      atomicAdd(&accum[(long)g * N2 + n0 + cl], v);
  }
}

// ---------------- finalize: out = accum / 50 (f32) ----------------
__global__ void finalize(const float* __restrict__ accum, float* __restrict__ out) {
  int idx = blockIdx.x * 256 + threadIdx.x;
  out[idx] = accum[idx] * (1.0f / 50.0f);
}

extern "C" void kernel_launch(void* const* d_in, const int* in_sizes, int n_in,
                              void* d_out, int out_size, void* d_ws, size_t ws_size,
                              hipStream_t stream) {
  const float* emb  = (const float*)d_in[0];
  const float* vis  = (const float*)d_in[1];
  const float* bbox = (const float*)d_in[2];
  const float* kp   = (const float*)d_in[3];
  const int*   mask = (const int*)d_in[4];
  const float* w1   = (const float*)d_in[5];
  const float* b1   = (const float*)d_in[6];
  const float* w2   = (const float*)d_in[7];
  const float* b2   = (const float*)d_in[8];
  float* out = (float*)d_out;

  // ws layout (bytes), all 16B aligned
  char* ws = (char*)d_ws;
  ushort_t* w1t    = (ushort_t*)(ws);               //  9,191,424  (2176*2112*2)
  ushort_t* w2t    = (ushort_t*)(ws +  9191424);    //  4,325,376  (1024*2112*2)
  float*    xtailf = (float*)   (ws + 13516800);    // 13,107,200  (51200*64*4)
  float*    accum  = (float*)   (ws + 26624000);    //  4,194,304  (1024*1024*4)
  ushort_t* H      = (ushort_t*)(ws + 30818304);    //  per-chunk: tiles*128*2112*2

  // dynamic chunking so H fits in the remaining workspace
  const size_t fixed_bytes = 30818304;
  const size_t per_tile = (size_t)BM * K1P * 2;     // 540,672 B
  int max_tiles = MTILES;
  if (ws_size > fixed_bytes + per_tile) {
    size_t avail = (ws_size - fixed_bytes) / per_tile;
    if (avail < (size_t)max_tiles) max_tiles = (int)avail;
  } else {
    max_tiles = 1;
  }
  if (max_tiles < 1) max_tiles = 1;

  pack_w1t<<<dim3(9, N1P), 256, 0, stream>>>(w1, w1t);
  pack_w2t<<<dim3(9, N2), 256, 0, stream>>>(w2, w2t);
  pack_xtail<<<dim3(M_TOTAL * 64 / 256), 256, 0, stream>>>(vis, bbox, kp, xtailf);
  zero_accum<<<dim3(NGRP * N2 / 256), 256, 0, stream>>>(accum);

  for (int t0 = 0; t0 < MTILES; t0 += max_tiles) {
    int tc = (MTILES - t0 < max_tiles) ? (MTILES - t0) : max_tiles;
    gemm1<<<dim3(N1P / BN, tc), 256, 0, stream>>>(emb, xtailf, w1t, b1, H, t0 * BM);
    gemm2<<<dim3(N2  / BN, tc), 256, 0, stream>>>(H, w2t, b2, mask, accum, t0 * BM);
  }

  finalize<<<dim3(NGRP * N2 / 256), 256, 0, stream>>>(accum, out);
}